// Round 11
// baseline (138.507 us; speedup 1.0000x reference)
//
#include <hip/hip_runtime.h>
#include <math.h>

typedef unsigned short ushort_t;
typedef __attribute__((ext_vector_type(8))) short short8;
typedef __attribute__((ext_vector_type(4))) float f32x4;

// ---- workspace byte offsets ----
#define OFF_TREP 0u          // f32 [1024][256]
#define OFF_AGG  1048576u    // f32 [256]  (zeroed by k_gemm task 443)
#define OFF_SCE  1049600u    // f32 [4000]
#define OFF_UT   1065600u    // bf16 [3][256][256]  Ut[s][j][d] = U[s][d][j]
#define OFF_VT   1458816u    // bf16 [128][256]     Vt[c2][d]  = V[d][c2]
#define OFF_C    1524352u    // f32 [3][256]
#define OFF_CS   1527424u    // f32 [128]
#define OFF_AB   1527936u    // bf16 [3][1000][256]  (b1 folded in)
#define OFF_BB   3063936u    // bf16 [3][1000][256]
#define OFF_Z    4599936u    // bf16 [3][4000][256]

__device__ __forceinline__ ushort_t f2bf(float f) {
    unsigned u = __builtin_bit_cast(unsigned, f);
    return (ushort_t)((u + 0x7FFFu + ((u >> 16) & 1u)) >> 16);
}
__device__ __forceinline__ float bf2f(ushort_t u) {
    unsigned v = ((unsigned)u) << 16;
    return __builtin_bit_cast(float, v);
}
__device__ __forceinline__ short8 ld8(const ushort_t* p) {
    return *(const short8*)(const void*)p;
}
__device__ __forceinline__ short8 cvt8(f32x4 a, f32x4 b) {
    short8 r;
#pragma unroll
    for (int j = 0; j < 4; j++) { r[j] = (short)f2bf(a[j]); r[j + 4] = (short)f2bf(b[j]); }
    return r;
}

// ---- P1 (self-contained): MFMA GEMMs from raw fp32 inputs.
//   tasks 0..383  : A/B halves (bf16 out)  (A = nf rows in-reg cvt; B = W1 k-half col-block LDS-transposed)
//   tasks 384..431: Ut          (A = Wa1_s col-block LDS-transposed; B = W2 rows in-reg cvt)
//   tasks 432..439: Vt          (A = Ws1 col-block LDS-transposed;  B = W2[0] rows in-reg cvt)
//   tasks 440..442: cvec[s] = b2[s] @ Wa1_s
//   task  443     : csv = b2[0] @ Ws1 + bs1 ; agg[0..255] = 0
__global__ __launch_bounds__(256) void k_gemm(const float* __restrict__ nf,
                                              const float* __restrict__ W1,
                                              const float* __restrict__ b1,
                                              const float* __restrict__ W2,
                                              const float* __restrict__ b2,
                                              const float* __restrict__ Ws1,
                                              const float* __restrict__ bs1,
                                              const float* __restrict__ Wa1,
                                              char* __restrict__ ws) {
    ushort_t* Ut   = (ushort_t*)(ws + OFF_UT);
    ushort_t* Vt   = (ushort_t*)(ws + OFF_VT);
    float*    cvec = (float*)(ws + OFF_C);
    float*    csv  = (float*)(ws + OFF_CS);
    ushort_t* Ab   = (ushort_t*)(ws + OFF_AB);
    ushort_t* Bb   = (ushort_t*)(ws + OFF_BB);
    float*    agg  = (float*)(ws + OFF_AGG);
    __shared__ ushort_t blds[64][264];   // +8 shorts pad: 16B-aligned rows
    int t = threadIdx.x, task = blockIdx.x;
    int wid = t >> 6, lane = t & 63;
    int lane15 = lane & 15, kb = lane >> 4;

    if (task < 384) {
        // ---- A/B tiles: C[row][col] = sum_k nf[row][k] * W1[s][half*256+k][col] (+b1 for half 0)
        int s = task / 128, rem = task % 128;
        int rb = rem >> 3, cb8 = rem & 7, half = cb8 >> 2, cbl = cb8 & 3;
        // half offsets W1's k-dim (rows, x65536 floats), NOT the d-dim (r6 fix).
        const float* w1p = W1 + s * 131072 + half * 65536 + cbl * 64;
        {   // LDS <- W1 block transposed: blds[dl][k] = W1[s][half*256+k][cbl*64+dl]
            int dl = t & 63, kq = t >> 6;
            for (int i = 0; i < 64; i++) {
                int k = i * 4 + kq;
                blds[dl][k] = f2bf(w1p[k * 256 + dl]);
            }
        }
        __syncthreads();
        int rowbase = rb * 64 + wid * 16;
        int lrow = min(rowbase + lane15, 999);
        const float* ap = nf + lrow * 256 + kb * 8;
        f32x4 acc[4] = {};
#pragma unroll
        for (int k0 = 0; k0 < 8; k0++) {
            f32x4 a0 = *(const f32x4*)(ap + k0 * 32);
            f32x4 a1 = *(const f32x4*)(ap + k0 * 32 + 4);
            short8 af = cvt8(a0, a1);
#pragma unroll
            for (int ct = 0; ct < 4; ct++)
                acc[ct] = __builtin_amdgcn_mfma_f32_16x16x32_bf16(
                    af, ld8(&blds[ct * 16 + lane15][kb * 8 + k0 * 32]), acc[ct], 0, 0, 0);
        }
        ushort_t* Cf = (half ? Bb : Ab) + s * 256000;
        int rb2 = rowbase + kb * 4;
#pragma unroll
        for (int ct = 0; ct < 4; ct++) {
            int col = cbl * 64 + ct * 16 + lane15;
            float bias = half ? 0.f : b1[s * 256 + col];
#pragma unroll
            for (int r = 0; r < 4; r++) {
                int row = rb2 + r;
                if (row < 1000) Cf[row * 256 + col] = f2bf(acc[ct][r] + bias);
            }
        }
    } else if (task < 440) {
        // ---- Ut/Vt tiles: C[row][col] = sum_e Asrc[e][rb0+row] * Bsrc[col][e]
        const float* Asrc; const float* Bsrc; ushort_t* Cout;
        int a_ld, rb0, colbase;
        if (task < 432) {
            int t2 = task - 384, s = t2 >> 4, rem = t2 & 15;
            rb0 = (rem >> 2) * 64; colbase = (rem & 3) * 64;
            Asrc = Wa1 + s * 65536; a_ld = 256;
            Bsrc = W2 + s * 65536;  Cout = Ut + s * 65536;
        } else {
            int t3 = task - 432;
            rb0 = (t3 >> 2) * 64; colbase = (t3 & 3) * 64;
            Asrc = Ws1; a_ld = 128;
            Bsrc = W2;  Cout = Vt;
        }
        {   // LDS <- Asrc col-block transposed: blds[el][e] = Asrc[e][rb0+el]
            int el = t & 63, eq = t >> 6;
            for (int i = 0; i < 64; i++) {
                int e = i * 4 + eq;
                blds[el][e] = f2bf(Asrc[e * a_ld + rb0 + el]);
            }
        }
        __syncthreads();
        int rowloc = wid * 16 + lane15;
        f32x4 acc[4] = {};
#pragma unroll
        for (int k0 = 0; k0 < 8; k0++) {
            short8 af = ld8(&blds[rowloc][kb * 8 + k0 * 32]);
#pragma unroll
            for (int ct = 0; ct < 4; ct++) {
                const float* bp = Bsrc + (colbase + ct * 16 + lane15) * 256 + kb * 8 + k0 * 32;
                f32x4 b0 = *(const f32x4*)bp;
                f32x4 b1v = *(const f32x4*)(bp + 4);
                acc[ct] = __builtin_amdgcn_mfma_f32_16x16x32_bf16(
                    af, cvt8(b0, b1v), acc[ct], 0, 0, 0);
            }
        }
        int rowg = rb0 + wid * 16 + kb * 4;
#pragma unroll
        for (int ct = 0; ct < 4; ct++) {
            int col = colbase + ct * 16 + lane15;
#pragma unroll
            for (int r = 0; r < 4; r++)
                Cout[(rowg + r) * 256 + col] = f2bf(acc[ct][r]);
        }
    } else if (task < 443) {
        int s = task - 440;
        float acc = 0.f;
        for (int k = 0; k < 256; k++) acc = fmaf(b2[s * 256 + k], Wa1[(s * 256 + k) * 256 + t], acc);
        cvec[s * 256 + t] = acc;
    } else {
        agg[t] = 0.f;   // replaces the hipMemsetAsync dispatch (runs before k_agg)
        if (t < 128) {
            float acc = bs1[t];
            for (int k = 0; k < 256; k++) acc = fmaf(b2[k], Ws1[k * 128 + t], acc);
            csv[t] = acc;
        }
    }
}

// ---- P2: H in registers -> Z(bf16) = H @ U.
//   Z-tiles: 32 rows x 256 cols (375 blocks): wave w = (row-strip w&1, col-half w>>1),
//   so each edge-row is gathered exactly ONCE per kernel (was 2x with 128-col tiles).
//   Score tiles (63): unchanged 64r x 128 V-cols. ----
__global__ __launch_bounds__(256, 4) void k_hz(const int* __restrict__ paths,
                                               const float* __restrict__ Ws2,
                                               const float* __restrict__ bs2,
                                               char* __restrict__ ws) {
    const ushort_t* Ab = (const ushort_t*)(ws + OFF_AB);
    const ushort_t* Bb = (const ushort_t*)(ws + OFF_BB);
    const ushort_t* Ut = (const ushort_t*)(ws + OFF_UT);
    const ushort_t* Vt = (const ushort_t*)(ws + OFF_VT);
    const float* csv = (const float*)(ws + OFF_CS);
    ushort_t* Zb = (ushort_t*)(ws + OFF_Z);
    float* sce = (float*)(ws + OFF_SCE);

    int task = blockIdx.x;               // 0..374 Z-tiles (32r x 256c), 375..437 score-tiles
    int t = threadIdx.x;
    int wid = t >> 6, lane = t & 63;
    int lane15 = lane & 15, kb = lane >> 4;
    int s, rb, iscore;
    if (task < 375) { s = task / 125; rb = task % 125; iscore = 0; }
    else            { s = 0; rb = task - 375; iscore = 1; }

    int rowbase, colbase;
    if (!iscore) { rowbase = rb * 32 + (wid & 1) * 16; colbase = (wid >> 1) * 128; }
    else         { rowbase = rb * 64 + wid * 16;       colbase = 0; }

    int erow = min(rowbase + lane15, 3999);
    int src = erow >> 2;
    int dst = paths[erow * 4 + 1];
    const ushort_t* ap = Ab + (s * 1000 + src) * 256 + kb * 8;
    const ushort_t* bp = Bb + (s * 1000 + dst) * 256 + kb * 8;

    short8 hfrag[8];
#pragma unroll
    for (int k0 = 0; k0 < 8; k0++) {
        short8 a8 = ld8(ap + k0 * 32);
        short8 b8 = ld8(bp + k0 * 32);
        short8 hf;
#pragma unroll
        for (int j = 0; j < 8; j++) {
            float v = bf2f((ushort_t)a8[j]) + bf2f((ushort_t)b8[j]);
            hf[j] = (short)f2bf(fmaxf(v, 0.f));
        }
        hfrag[k0] = hf;
    }

    int rb2 = rowbase + kb * 4;
    if (!iscore) {
        const ushort_t* up = Ut + s * 65536 + (colbase + lane15) * 256 + kb * 8;
        f32x4 acc[8] = {};
#pragma unroll
        for (int k0 = 0; k0 < 8; k0++) {
            short8 af = hfrag[k0];
#pragma unroll
            for (int ct = 0; ct < 8; ct++)
                acc[ct] = __builtin_amdgcn_mfma_f32_16x16x32_bf16(
                    af, ld8(up + ct * 4096 + k0 * 32), acc[ct], 0, 0, 0);
        }
#pragma unroll
        for (int ct = 0; ct < 8; ct++) {
            int col = colbase + ct * 16 + lane15;
#pragma unroll
            for (int r = 0; r < 4; r++) {
                int row = rb2 + r;
                if (row < 4000) Zb[(s * 4000 + row) * 256 + col] = f2bf(acc[ct][r]);
            }
        }
    } else {
        const ushort_t* vp = Vt + lane15 * 256 + kb * 8;
        f32x4 acc2[8] = {};
#pragma unroll
        for (int k0 = 0; k0 < 8; k0++) {
            short8 af = hfrag[k0];
#pragma unroll
            for (int ct = 0; ct < 8; ct++)
                acc2[ct] = __builtin_amdgcn_mfma_f32_16x16x32_bf16(
                    af, ld8(vp + ct * 4096 + k0 * 32), acc2[ct], 0, 0, 0);
        }
        float w2v[8], cv[8];
#pragma unroll
        for (int ct = 0; ct < 8; ct++) {
            int col = ct * 16 + lane15;
            w2v[ct] = Ws2[col]; cv[ct] = csv[col];
        }
        float bb = bs2[0];
#pragma unroll
        for (int r = 0; r < 4; r++) {
            float y = 0.f;
#pragma unroll
            for (int ct = 0; ct < 8; ct++) y += fmaxf(acc2[ct][r] + cv[ct], 0.f) * w2v[ct];
            y += __shfl_xor(y, 1, 64); y += __shfl_xor(y, 2, 64);
            y += __shfl_xor(y, 4, 64); y += __shfl_xor(y, 8, 64);
            int row = rb2 + r;
            if (lane15 == 0 && row < 4000)
                sce[row] = 1.f / (1.f + expf(-(y + bb)));
        }
    }
}

// ---- P3: path relu-sums -> per-block Trep row; score scatter ----
__global__ __launch_bounds__(256) void k_path(const int* __restrict__ paths,
                                              const float* __restrict__ ba1,
                                              char* __restrict__ ws,
                                              float* __restrict__ out) {
    const ushort_t* Zb = (const ushort_t*)(ws + OFF_Z);
    const float* cvec  = (const float*)(ws + OFF_C);
    const float* sce   = (const float*)(ws + OFF_SCE);
    float* Trep = (float*)(ws + OFF_TREP);
    int t = threadIdx.x;
    float zb2 = ba1[t] + cvec[t];
    float zb3 = zb2 + cvec[256 + t];
    float zb4 = zb3 + cvec[512 + t];
    const ushort_t* Z0 = Zb;
    const ushort_t* Z1 = Zb + 1024000;
    const ushort_t* Z2 = Zb + 2048000;
    float acc = 0.f;
    for (int b = blockIdx.x; b < 4000; b += 1024) {
        float z0 = bf2f(Z0[b * 256 + t]);
        acc += fmaxf(zb2 + z0, 0.f);
#pragma unroll
        for (int j = 0; j < 4; j++) {
            int q = b * 4 + j;
            int n1 = paths[(4000 + q) * 4 + 1];
            float w = z0 + bf2f(Z1[(n1 * 4 + j) * 256 + t]);
            acc += fmaxf(zb3 + w, 0.f);
            int n2 = paths[(4000 + q) * 4 + 2];
            const ushort_t* z2p = Z2 + n2 * 1024 + t;
            acc += fmaxf(zb4 + w + bf2f(z2p[0]),   0.f);
            acc += fmaxf(zb4 + w + bf2f(z2p[256]), 0.f);
            acc += fmaxf(zb4 + w + bf2f(z2p[512]), 0.f);
            acc += fmaxf(zb4 + w + bf2f(z2p[768]), 0.f);
        }
    }
    Trep[blockIdx.x * 256 + t] = acc;
    int p = blockIdx.x * 256 + t;
    if (p < 84000) {
        int e0 = p < 4000 ? p : (p < 20000 ? ((p - 4000) >> 2) : ((p - 20000) >> 4));
        out[256000 + p] = sce[e0];
    }
}

// ---- P4: agg[d] += (sum of 32 Trep rows) @ Wa2 (atomic into 256-float agg) ----
__global__ __launch_bounds__(256) void k_agg(const float* __restrict__ Wa2,
                                             char* __restrict__ ws) {
    const float* Trep = (const float*)(ws + OFF_TREP);
    float* agg = (float*)(ws + OFF_AGG);
    __shared__ float tl[256];
    int t = threadIdx.x, i = blockIdx.x;
    float ts = 0.f;
#pragma unroll 8
    for (int r = 0; r < 32; r++) ts += Trep[(i * 32 + r) * 256 + t];
    tl[t] = ts;
    __syncthreads();
    float acc = 0.f;
    for (int k = 0; k < 256; k++) acc = fmaf(tl[k], Wa2[k * 256 + t], acc);
    atomicAdd(&agg[t], acc);
}

// ---- P5: out = nf + agg + 84000*ba2 (float4) ----
__global__ __launch_bounds__(256) void k_fin(const float* __restrict__ nf,
                                             const float* __restrict__ ba2,
                                             char* __restrict__ ws,
                                             float* __restrict__ out) {
    const float* agg = (const float*)(ws + OFF_AGG);
    int gid = blockIdx.x * 256 + threadIdx.x;   // < 64000
    int d0 = (gid * 4) & 255;
    f32x4 x = *(const f32x4*)(nf + gid * 4);
    f32x4 a = *(const f32x4*)(agg + d0);
    f32x4 b = *(const f32x4*)(ba2 + d0);
#pragma unroll
    for (int j = 0; j < 4; j++) x[j] += a[j] + 84000.f * b[j];
    *(f32x4*)(out + gid * 4) = x;
}

extern "C" void kernel_launch(void* const* d_in, const int* in_sizes, int n_in,
                              void* d_out, int out_size, void* d_ws, size_t ws_size,
                              hipStream_t stream) {
    const float* nf    = (const float*)d_in[0];
    const int*   paths = (const int*)d_in[1];
    // d_in[2] = path_len (regions derived from index)
    const float* W1    = (const float*)d_in[3];
    const float* b1    = (const float*)d_in[4];
    const float* W2    = (const float*)d_in[5];
    const float* b2    = (const float*)d_in[6];
    const float* Ws1   = (const float*)d_in[7];
    const float* bs1   = (const float*)d_in[8];
    const float* Ws2   = (const float*)d_in[9];
    const float* bs2   = (const float*)d_in[10];
    const float* Wa1   = (const float*)d_in[11];
    const float* ba1   = (const float*)d_in[12];
    const float* Wa2   = (const float*)d_in[13];
    const float* ba2   = (const float*)d_in[14];
    char* ws = (char*)d_ws;
    float* out = (float*)d_out;

    k_gemm<<<444, 256, 0, stream>>>(nf, W1, b1, W2, b2, Ws1, bs1, Wa1, ws);
    k_hz  <<<438, 256, 0, stream>>>(paths, Ws2, bs2, ws);
    k_path<<<1024, 256, 0, stream>>>(paths, ba1, ws, out);
    k_agg <<<32, 256, 0, stream>>>(Wa2, ws);
    k_fin <<<250, 256, 0, stream>>>(nf, ba2, ws, out);
}